// Round 6
// baseline (634.199 us; speedup 1.0000x reference)
//
#include <hip/hip_runtime.h>
#include <stdint.h>
#include <stddef.h>

// Problem constants (reference: NB=4, B=16, C=256, L=4096)
#define NBR 4
#define BSZ 16
#define CHN 256
#define LEN 4096
#define NB_B 64            // NBR*BSZ
#define BL   65536         // BSZ*LEN
#define BN_EPS 1e-5f
#define W_EL (NBR*CHN*CHN) // 262144 elements per weight tensor

typedef unsigned short ushortT;
typedef unsigned short ushort4_t __attribute__((ext_vector_type(4)));
typedef unsigned short ushort8_t __attribute__((ext_vector_type(8)));
typedef short bf16x8 __attribute__((ext_vector_type(8)));
typedef float f32x4 __attribute__((ext_vector_type(4)));

__device__ __forceinline__ float bf2f(ushortT u) {
    return __uint_as_float(((unsigned)u) << 16);
}
__device__ __forceinline__ ushortT f2bf(float f) {
    unsigned b = __float_as_uint(f);
    return (ushortT)((b + 0x7FFFu + ((b >> 16) & 1u)) >> 16);
}
// order-preserving float->uint encoding (monotone); memset-0 init is below enc(-inf)
__device__ __forceinline__ unsigned encf(float f) {
    unsigned b = __float_as_uint(f);
    return (b & 0x80000000u) ? ~b : (b | 0x80000000u);
}
__device__ __forceinline__ float decf(unsigned u) {
    unsigned b = (u & 0x80000000u) ? (u ^ 0x80000000u) : ~u;
    return __uint_as_float(b);
}

// LDS swizzle for sX (byte offsets). Rows are 512B (256 c bf16).
__device__ __forceinline__ int swzX(int row, int cb) {
    return row * 512 + (cb ^ ((row & 7) << 4) ^ (((row >> 3) & 3) << 7));
}

// Stage x-tile [l=128][c=256] into LDS, transposed+converted, swizzled.
// Loads are coalesced per wave-instruction (lane -> l, 4B each).
__device__ __forceinline__ void stage_x_f32(const float* x, ushortT* sX, int z, int lbase, int tid)
{
    const int ls = tid & 127;
    const int gh = tid >> 7;
    const float* xp = x + (size_t)z * CHN * LEN + lbase + ls;
#pragma unroll
    for (int g = 0; g < 16; ++g) {
        int c0 = (gh * 16 + g) * 8;
        ushort8_t u;
#pragma unroll
        for (int i = 0; i < 8; ++i) u[i] = f2bf(xp[(size_t)(c0 + i) * LEN]);
        *(ushort8_t*)((char*)sX + swzX(ls, c0 * 2)) = u;
    }
}

// One K-chunk (64) of MFMA. W B-fragments loaded DIRECTLY from global (L2-resident,
// fragment = 8 contiguous k at row o -> a single 16B load, no LDS staging needed).
// SWAP=false: A = x (M=l), B = W (N=o), acc[mf][nf] row=l col=o.
// SWAP=true : A = W (M=o), B = x (N=l), acc[nf][mf] row=o col=l.
template <bool SWAP>
__device__ __forceinline__ void mfma_chunk_g(const ushortT* sX, const ushortT* __restrict__ Wb,
                                             int obase, f32x4 acc[4][4],
                                             int wr, int wc, int lane, int kb)
{
    const int am = wr * 64 + (lane & 15);
    const int orow = obase + wc * 64 + (lane & 15);
    const int kg = (lane >> 4) * 16;   // byte offset of this lane's k-group (LDS)
    const int ke = (lane >> 4) * 8;    // element offset (global)
#pragma unroll
    for (int s = 0; s < 2; ++s) {
        bf16x8 a[4], b[4];
#pragma unroll
        for (int nf = 0; nf < 4; ++nf)
            b[nf] = *(const bf16x8*)(Wb + (size_t)(orow + nf * 16) * CHN + kb * 64 + s * 32 + ke);
#pragma unroll
        for (int mf = 0; mf < 4; ++mf)
            a[mf] = *(const bf16x8*)((const char*)sX + swzX(am + mf * 16, kb * 128 + s * 64 + kg));
#pragma unroll
        for (int mf = 0; mf < 4; ++mf)
#pragma unroll
            for (int nf = 0; nf < 4; ++nf) {
                if (!SWAP)
                    acc[mf][nf] = __builtin_amdgcn_mfma_f32_16x16x32_bf16(a[mf], b[nf], acc[mf][nf], 0, 0, 0);
                else
                    acc[nf][mf] = __builtin_amdgcn_mfma_f32_16x16x32_bf16(b[nf], a[mf], acc[nf][mf], 0, 0, 0);
            }
    }
}

// ---------------------------------------------------------------------------
// QKV fused: stage x-tile once (1 barrier), then 6 barrier-free GEMM-tiles.
// Wq/Wk epilogue: per-o sum & max over l -> atomics.
// Wv: swapped-operand GEMM, BOTH o-halves accumulated before storing, so each
//     512B vT row is written in one burst (kills partial-sector write amp).
// ---------------------------------------------------------------------------
__global__ __launch_bounds__(256, 2)
void qkv_kernel(const float* __restrict__ x, const ushortT* __restrict__ Wbf,
                const float* __restrict__ bv,
                float* __restrict__ qsum, unsigned* __restrict__ qmax,
                float* __restrict__ ksum, unsigned* __restrict__ kmax,
                ushortT* __restrict__ vT)
{
    __shared__ ushortT sX[128 * 256];   // 64 KiB (only LDS)
    const int tid = threadIdx.x;
    const int lane = tid & 63;
    const int wv = tid >> 6;
    const int wr = wv >> 1, wc = wv & 1;
    const int lbase = blockIdx.x * 128;
    const int z = blockIdx.y;
    const int n = z >> 4;

    stage_x_f32(x, sX, z, lbase, tid);
    __syncthreads();                    // the only barrier in the kernel

    const f32x4 z4 = {0.f, 0.f, 0.f, 0.f};

    // ---- Q and K tiles: acc[mf][nf] row=l col=o ----
#pragma unroll
    for (int w = 0; w < 2; ++w) {
        const ushortT* Wb = Wbf + ((size_t)w * NBR + n) * CHN * CHN;
        float* rs = (w == 0) ? qsum : ksum;
        unsigned* rm = (w == 0) ? qmax : kmax;
        for (int ot = 0; ot < 2; ++ot) {
            const int obase = ot * 128;
            f32x4 acc[4][4];
#pragma unroll
            for (int mf = 0; mf < 4; ++mf)
#pragma unroll
                for (int nf = 0; nf < 4; ++nf) acc[mf][nf] = z4;
#pragma unroll
            for (int kb = 0; kb < 4; ++kb)
                mfma_chunk_g<false>(sX, Wb, obase, acc, wr, wc, lane, kb);

#pragma unroll
            for (int nf = 0; nf < 4; ++nf) {
                float s = 0.f, m = -3.4e38f;
#pragma unroll
                for (int mf = 0; mf < 4; ++mf)
#pragma unroll
                    for (int r = 0; r < 4; ++r) {
                        float v = acc[mf][nf][r];
                        s += v; m = fmaxf(m, v);
                    }
                s += __shfl_xor(s, 16); s += __shfl_xor(s, 32);
                m = fmaxf(m, __shfl_xor(m, 16)); m = fmaxf(m, __shfl_xor(m, 32));
                if (lane < 16) {
                    int o = obase + wc * 64 + nf * 16 + lane;
                    atomicAdd(&rs[z * CHN + o], s);
                    atomicMax(&rm[z * CHN + o], encf(m));
                }
            }
        }
    }

    // ---- V tile: both o-halves, acc[nf][mf] row=o col=l ----
    {
        const ushortT* Wb = Wbf + ((size_t)2 * NBR + n) * CHN * CHN;
        f32x4 acc[4][4], acc2[4][4];
#pragma unroll
        for (int i = 0; i < 4; ++i)
#pragma unroll
            for (int j = 0; j < 4; ++j) { acc[i][j] = z4; acc2[i][j] = z4; }
#pragma unroll
        for (int kb = 0; kb < 4; ++kb)
            mfma_chunk_g<true>(sX, Wb, 0, acc, wr, wc, lane, kb);
#pragma unroll
        for (int kb = 0; kb < 4; ++kb)
            mfma_chunk_g<true>(sX, Wb, 128, acc2, wr, wc, lane, kb);

#pragma unroll
        for (int nf = 0; nf < 4; ++nf) {
            const int c128 = wc * 64 + nf * 16 + ((lane >> 4) << 2);
            float b0[4], b1[4];
#pragma unroll
            for (int r = 0; r < 4; ++r) {
                b0[r] = bv[n * CHN + c128 + r];
                b1[r] = bv[n * CHN + 128 + c128 + r];
            }
#pragma unroll
            for (int mf = 0; mf < 4; ++mf) {
                const int l = lbase + wr * 64 + mf * 16 + (lane & 15);
                const size_t rowb = ((size_t)z * LEN + l) * CHN;
                ushort4_t u0, u1;
#pragma unroll
                for (int r = 0; r < 4; ++r) {
                    u0[r] = f2bf(acc[nf][mf][r] + b0[r]);
                    u1[r] = f2bf(acc2[nf][mf][r] + b1[r]);
                }
                *(ushort4_t*)(vT + rowb + c128) = u0;
                *(ushort4_t*)(vT + rowb + 128 + c128) = u1;
            }
        }
    }
}

// ---------------------------------------------------------------------------
// O GEMM with fused aggregation: agg[i,b,:,l] = sum_j attn[i,j,b] * v[j,b,:,l]
// read from vT[z][l][c] (coalesced ushort8), combined in-reg -> sX (1 barrier),
// then barrier-free Wo GEMM -> out_pre[z][c][l] (bf16) + BN partial stats.
// ---------------------------------------------------------------------------
__global__ __launch_bounds__(256, 2)
void ogemm_kernel(const ushortT* __restrict__ vT, const ushortT* __restrict__ Wbo,
                  const float* __restrict__ attn, const float* __restrict__ bo_,
                  float* __restrict__ bnsum, float* __restrict__ bnss,
                  ushortT* __restrict__ outpre)
{
    __shared__ ushortT sX[128 * 256];
    const int tid = threadIdx.x;
    const int lane = tid & 63;
    const int wv = tid >> 6;
    const int wr = wv >> 1, wc = wv & 1;
    const int lbase = blockIdx.x * 128;
    const int z = blockIdx.y;
    const int n = z >> 4;          // output branch i
    const int b_ = z & 15;
    const ushortT* Wb = Wbo + (size_t)n * CHN * CHN;

    float aj[4];
#pragma unroll
    for (int j = 0; j < 4; ++j) aj[j] = attn[(n * 4 + j) * BSZ + b_];

    // ---- stage agg tile: 4x coalesced vT reads + weighted combine -> sX ----
#pragma unroll 4
    for (int u = 0; u < 16; ++u) {
        int g = u * 256 + tid;
        int l = g >> 5;                  // 0..127
        int cg = g & 31;                 // ushort8 group along c
        size_t boff = ((size_t)lbase + l) * CHN + cg * 8;
        float acc8[8];
#pragma unroll
        for (int e = 0; e < 8; ++e) acc8[e] = 0.f;
#pragma unroll
        for (int j = 0; j < 4; ++j) {
            ushort8_t r8 = *(const ushort8_t*)(vT + (size_t)(j * BSZ + b_) * LEN * CHN + boff);
#pragma unroll
            for (int e = 0; e < 8; ++e) acc8[e] += aj[j] * bf2f(r8[e]);
        }
        ushort8_t o8;
#pragma unroll
        for (int e = 0; e < 8; ++e) o8[e] = f2bf(acc8[e]);
        *(ushort8_t*)((char*)sX + swzX(l, cg * 16)) = o8;
    }
    __syncthreads();                    // the only barrier

    for (int ot = 0; ot < 2; ++ot) {
        const int obase = ot * 128;
        f32x4 acc[4][4];
        const f32x4 z4 = {0.f, 0.f, 0.f, 0.f};
#pragma unroll
        for (int mf = 0; mf < 4; ++mf)
#pragma unroll
            for (int nf = 0; nf < 4; ++nf) acc[mf][nf] = z4;
#pragma unroll
        for (int kb = 0; kb < 4; ++kb)
            mfma_chunk_g<false>(sX, Wb, obase, acc, wr, wc, lane, kb);

#pragma unroll
        for (int nf = 0; nf < 4; ++nf) {
            int o = obase + wc * 64 + nf * 16 + (lane & 15);
            float bb = bo_[n * CHN + o];
            float s = 0.f, q2 = 0.f;
#pragma unroll
            for (int mf = 0; mf < 4; ++mf) {
                int l = lbase + wr * 64 + mf * 16 + ((lane >> 4) << 2);
                ushort4_t u;
#pragma unroll
                for (int r = 0; r < 4; ++r) {
                    float v = acc[mf][nf][r] + bb;
                    u[r] = f2bf(v);
                    s += v; q2 += v * v;
                }
                *(ushort4_t*)(outpre + (size_t)(z * CHN + o) * LEN + l) = u;
            }
            s += __shfl_xor(s, 16); s += __shfl_xor(s, 32);
            q2 += __shfl_xor(q2, 16); q2 += __shfl_xor(q2, 32);
            if (lane < 16) {
                atomicAdd(&bnsum[n * CHN + o], s);
                atomicAdd(&bnss[n * CHN + o], q2);
            }
        }
    }
}

// convert all 4 weight tensors fp32 -> bf16 into Wbf [w][n][o][c]
__global__ void wcvt_kernel(const float* __restrict__ Wq, const float* __restrict__ Wk,
                            const float* __restrict__ Wv, const float* __restrict__ Wo,
                            ushortT* __restrict__ Wbf)
{
    int t = blockIdx.x * 256 + threadIdx.x;    // float4 units
    const int per = W_EL / 4;                  // 65536
    if (t < 4 * per) {
        const float* srcs[4] = {Wq, Wk, Wv, Wo};
        int w = t / per;
        int r = t - w * per;
        float4 f = *(const float4*)(srcs[w] + (size_t)r * 4);
        ushort4_t u = {f2bf(f.x), f2bf(f.y), f2bf(f.z), f2bf(f.w)};
        *(ushort4_t*)(Wbf + (size_t)w * W_EL + (size_t)r * 4) = u;
    }
}

// ---------------------------------------------------------------------------
// attention coefficients: scores[i,j,b] = (sum_c sq*sk) * edge_w[i,j] / 64
// attn[i,j,b] = softmax_j(scores) * softmax(branch_imp)[j]
// sq = qsum/L + dec(qmax) + 2*bq  (mean+max, bias shifts both by bq)
// ---------------------------------------------------------------------------
__global__ void attn_kernel(const float* __restrict__ qsum, const unsigned* __restrict__ qmax,
                            const float* __restrict__ ksum, const unsigned* __restrict__ kmax,
                            const float* __restrict__ bq, const float* __restrict__ bk,
                            const float* __restrict__ edge, const float* __restrict__ bimp,
                            float* __restrict__ attn)
{
    __shared__ float sc[NBR][NBR][BSZ];
    int tid = threadIdx.x;           // 256 threads == 4*4*16
    int i = tid >> 6, j = (tid >> 4) & 3, b = tid & 15;
    float s = 0.f;
    const float invL = 1.0f / (float)LEN;
    for (int c = 0; c < CHN; ++c) {
        int qi = (i * BSZ + b) * CHN + c;
        int ki = (j * BSZ + b) * CHN + c;
        float sq = qsum[qi] * invL + decf(qmax[qi]) + 2.f * bq[i * CHN + c];
        float sk = ksum[ki] * invL + decf(kmax[ki]) + 2.f * bk[j * CHN + c];
        s += sq * sk;
    }
    sc[i][j][b] = s * edge[i * 4 + j] * (1.0f / 64.0f);
    __syncthreads();
    if (tid < 64) {
        int ii = tid >> 4, bb = tid & 15;
        float m = -3.4e38f;
        for (int jj = 0; jj < 4; ++jj) m = fmaxf(m, sc[ii][jj][bb]);
        float e[4]; float sum = 0.f;
        for (int jj = 0; jj < 4; ++jj) { e[jj] = __expf(sc[ii][jj][bb] - m); sum += e[jj]; }
        float bm = fmaxf(fmaxf(bimp[0], bimp[1]), fmaxf(bimp[2], bimp[3]));
        float be[4]; float bs = 0.f;
        for (int jj = 0; jj < 4; ++jj) { be[jj] = __expf(bimp[jj] - bm); bs += be[jj]; }
        for (int jj = 0; jj < 4; ++jj)
            attn[(ii * 4 + jj) * BSZ + bb] = (e[jj] / sum) * (be[jj] / bs);
    }
}

// finalize BN affine: scale = gamma*rsqrt(var+eps), shift = beta - mean*scale
__global__ void bnfin_kernel(const float* __restrict__ bnsum, const float* __restrict__ bnss,
                             const float* __restrict__ gamma, const float* __restrict__ beta,
                             float* __restrict__ scl, float* __restrict__ shf)
{
    int t = blockIdx.x * blockDim.x + threadIdx.x;   // 0..1023 = n*256+c
    if (t < NBR * CHN) {
        const float inv = 1.0f / (float)BL;
        float mean = bnsum[t] * inv;
        float var = bnss[t] * inv - mean * mean;
        float rs = rsqrtf(var + BN_EPS);
        float s = gamma[t] * rs;
        scl[t] = s;
        shf[t] = beta[t] - mean * s;
    }
}

// out = relu(out_pre*scale + shift) + x
__global__ __launch_bounds__(256)
void final_kernel(const ushortT* __restrict__ outpre, const float* __restrict__ x,
                  const float* __restrict__ scl, const float* __restrict__ shf,
                  float* __restrict__ out)
{
    const long long U = (long long)NB_B * CHN * (LEN / 8);   // 8,388,608 units of 8
    for (long long u = (long long)blockIdx.x * blockDim.x + threadIdx.x; u < U;
         u += (long long)gridDim.x * blockDim.x) {
        int l0 = (int)(u & 511) * 8;
        int c  = (int)(u >> 9) & 255;
        int zz = (int)(u >> 17);          // n*16+b
        int n  = zz >> 4;
        size_t base = ((size_t)zz * CHN + c) * LEN + l0;
        ushort8_t op = *(const ushort8_t*)(outpre + base);
        float4 x0 = *(const float4*)(x + base);
        float4 x1 = *(const float4*)(x + base + 4);
        float sc = scl[n * CHN + c];
        float sh = shf[n * CHN + c];
        float xr[8] = {x0.x, x0.y, x0.z, x0.w, x1.x, x1.y, x1.z, x1.w};
        float res[8];
#pragma unroll
        for (int e = 0; e < 8; ++e) {
            float bn = bf2f(op[e]) * sc + sh;
            res[e] = fmaxf(bn, 0.f) + xr[e];
        }
        float4 o0 = {res[0], res[1], res[2], res[3]};
        float4 o1 = {res[4], res[5], res[6], res[7]};
        *(float4*)(out + base) = o0;
        *(float4*)(out + base + 4) = o1;
    }
}

extern "C" void kernel_launch(void* const* d_in, const int* in_sizes, int n_in,
                              void* d_out, int out_size, void* d_ws, size_t ws_size,
                              hipStream_t stream)
{
    const float* x     = (const float*)d_in[0];
    const float* Wq    = (const float*)d_in[1];
    const float* bq    = (const float*)d_in[2];
    const float* Wk    = (const float*)d_in[3];
    const float* bk    = (const float*)d_in[4];
    const float* Wv    = (const float*)d_in[5];
    const float* bv    = (const float*)d_in[6];
    const float* Wo    = (const float*)d_in[7];
    const float* bo    = (const float*)d_in[8];
    const float* gamma = (const float*)d_in[9];
    const float* beta  = (const float*)d_in[10];
    const float* edge  = (const float*)d_in[11];
    const float* bimp  = (const float*)d_in[12];

    char* ws = (char*)d_ws;
    const size_t P_BYTES = (size_t)NBR * BSZ * CHN * LEN * 2;   // 128 MiB (bf16)
    ushortT* outpre = (ushortT*)ws;          // out_pre staging (ws)
    size_t off = P_BYTES;
    float*    qsum = (float*)(ws + off);    off += 65536;
    unsigned* qmax = (unsigned*)(ws + off); off += 65536;
    float*    ksum = (float*)(ws + off);    off += 65536;
    unsigned* kmax = (unsigned*)(ws + off); off += 65536;
    float*    attn = (float*)(ws + off);    off += 1024;
    float*    bnsum= (float*)(ws + off);    off += 4096;
    float*    bnss = (float*)(ws + off);    off += 4096;
    float*    scl  = (float*)(ws + off);    off += 4096;
    float*    shf  = (float*)(ws + off);    off += 4096;

    // zero the small accumulators (sum=0; max uses encoding where 0 < enc(-inf))
    hipMemsetAsync(ws + P_BYTES, 0, off - P_BYTES, stream);

    // d_out scratch usage (dead by the time final_kernel rewrites d_out):
    //   [0, 128Mi):    vT  (bf16, [z][l][c]) written by qkv, read by ogemm
    //   [128Mi, +2Mi): Wbf (bf16 weights)    written by wcvt
    ushortT* vT  = (ushortT*)d_out;
    ushortT* Wbf = (ushortT*)((char*)d_out + ((size_t)134217728));
    float*   outf = (float*)d_out;

    wcvt_kernel<<<(4 * W_EL / 4 + 255) / 256, 256, 0, stream>>>(Wq, Wk, Wv, Wo, Wbf);

    dim3 gq(LEN / 128, NB_B);   // (32, 64)
    qkv_kernel<<<gq, 256, 0, stream>>>(x, Wbf, bv, qsum, qmax, ksum, kmax, vT);
    attn_kernel<<<1, 256, 0, stream>>>(qsum, qmax, ksum, kmax, bq, bk, edge, bimp, attn);
    ogemm_kernel<<<gq, 256, 0, stream>>>(vT, Wbf + (size_t)3 * W_EL, attn, bo, bnsum, bnss, outpre);
    bnfin_kernel<<<4, 256, 0, stream>>>(bnsum, bnss, gamma, beta, scl, shf);
    final_kernel<<<8192, 256, 0, stream>>>(outpre, x, scl, shf, outf);
}

// Round 7
// 521.647 us; speedup vs baseline: 1.2158x; 1.2158x over previous
//
#include <hip/hip_runtime.h>
#include <stdint.h>
#include <stddef.h>

// Problem constants (reference: NB=4, B=16, C=256, L=4096)
#define NBR 4
#define BSZ 16
#define CHN 256
#define LEN 4096
#define NB_B 64            // NBR*BSZ
#define BL   65536         // BSZ*LEN
#define BN_EPS 1e-5f
#define W_EL (NBR*CHN*CHN) // 262144 elements per weight tensor

typedef unsigned short ushortT;
typedef unsigned short ushort4_t __attribute__((ext_vector_type(4)));
typedef unsigned short ushort8_t __attribute__((ext_vector_type(8)));
typedef short bf16x8 __attribute__((ext_vector_type(8)));
typedef float f32x4 __attribute__((ext_vector_type(4)));

__device__ __forceinline__ float bf2f(ushortT u) {
    return __uint_as_float(((unsigned)u) << 16);
}
__device__ __forceinline__ ushortT f2bf(float f) {
    unsigned b = __float_as_uint(f);
    return (ushortT)((b + 0x7FFFu + ((b >> 16) & 1u)) >> 16);
}
// order-preserving float->uint encoding (monotone); memset-0 init is below enc(-inf)
__device__ __forceinline__ unsigned encf(float f) {
    unsigned b = __float_as_uint(f);
    return (b & 0x80000000u) ? ~b : (b | 0x80000000u);
}
__device__ __forceinline__ float decf(unsigned u) {
    unsigned b = (u & 0x80000000u) ? (u ^ 0x80000000u) : ~u;
    return __uint_as_float(b);
}

// LDS swizzle for sX (byte offsets). Rows are 512B (256 c bf16).
__device__ __forceinline__ int swzX(int row, int cb) {
    return row * 512 + (cb ^ ((row & 7) << 4) ^ (((row >> 3) & 3) << 7));
}

// Stage x-tile [l=128][c=256] into LDS, transposed+converted, swizzled.
// Loads are coalesced per wave-instruction (lane -> l).
__device__ __forceinline__ void stage_x_f32(const float* x, ushortT* sX, int z, int lbase, int tid)
{
    const int ls = tid & 127;
    const int gh = tid >> 7;
    const float* xp = x + (size_t)z * CHN * LEN + lbase + ls;
#pragma unroll
    for (int g = 0; g < 16; ++g) {
        int c0 = (gh * 16 + g) * 8;
        ushort8_t u;
#pragma unroll
        for (int i = 0; i < 8; ++i) u[i] = f2bf(xp[(size_t)(c0 + i) * LEN]);
        *(ushort8_t*)((char*)sX + swzX(ls, c0 * 2)) = u;
    }
}
__device__ __forceinline__ void stage_x_bf16(const ushortT* a, ushortT* sX, int z, int lbase, int tid)
{
    const int ls = tid & 127;
    const int gh = tid >> 7;
    const ushortT* xp = a + (size_t)z * CHN * LEN + lbase + ls;
#pragma unroll
    for (int g = 0; g < 16; ++g) {
        int c0 = (gh * 16 + g) * 8;
        ushort8_t u;
#pragma unroll
        for (int i = 0; i < 8; ++i) u[i] = xp[(size_t)(c0 + i) * LEN];
        *(ushort8_t*)((char*)sX + swzX(ls, c0 * 2)) = u;
    }
}

// One K-chunk (64 c) of MFMA. W B-fragments come straight from global in
// PRE-PACKED fragment order: Wb2[ob][cb][lane][8] -> each fragment load is
// base + lane*16B = one fully-coalesced 1KB dwordx4 per wave (L2-resident).
// A = x (M=l) from LDS, B = W (N=o). acc[mf][nf] row=l col=o.
__device__ __forceinline__ void mfma_chunk_frag(const ushortT* sX, const ushortT* __restrict__ Wb2,
                                                int otile, f32x4 acc[4][4],
                                                int wr, int wc, int lane, int kb)
{
    const int am = wr * 64 + (lane & 15);
    const int kg = (lane >> 4) * 16;   // byte offset of this lane's k-group (LDS)
#pragma unroll
    for (int s = 0; s < 2; ++s) {
        const int cb = kb * 2 + s;
        bf16x8 a[4], b[4];
#pragma unroll
        for (int nf = 0; nf < 4; ++nf) {
            const int ob = otile * 8 + wc * 4 + nf;
            b[nf] = *(const bf16x8*)(Wb2 + (((size_t)ob * 8 + cb) * 64 + lane) * 8);
        }
#pragma unroll
        for (int mf = 0; mf < 4; ++mf)
            a[mf] = *(const bf16x8*)((const char*)sX + swzX(am + mf * 16, kb * 128 + s * 64 + kg));
#pragma unroll
        for (int mf = 0; mf < 4; ++mf)
#pragma unroll
            for (int nf = 0; nf < 4; ++nf)
                acc[mf][nf] = __builtin_amdgcn_mfma_f32_16x16x32_bf16(a[mf], b[nf], acc[mf][nf], 0, 0, 0);
    }
}

// ---------------------------------------------------------------------------
// QKV fused: stage x-tile once (ONE barrier), then 6 barrier-free GEMM-tiles
// with coalesced fragment-order W loads from L2.
// Wq/Wk epilogue: per-o sum & max over l -> atomics. Wv: bias + bf16 store
// to vbuf[z][c][l] (the write pattern measured at ~ideal WRITE_SIZE).
// ---------------------------------------------------------------------------
__global__ __launch_bounds__(256, 2)
void qkv_kernel(const float* __restrict__ x, const ushortT* __restrict__ Wbf,
                const float* __restrict__ bv,
                float* __restrict__ qsum, unsigned* __restrict__ qmax,
                float* __restrict__ ksum, unsigned* __restrict__ kmax,
                ushortT* __restrict__ vbuf)
{
    __shared__ ushortT sX[128 * 256];   // 64 KiB (only LDS)
    const int tid = threadIdx.x;
    const int lane = tid & 63;
    const int wv = tid >> 6;
    const int wr = wv >> 1, wc = wv & 1;
    const int lbase = blockIdx.x * 128;
    const int z = blockIdx.y;
    const int n = z >> 4;

    stage_x_f32(x, sX, z, lbase, tid);
    __syncthreads();                    // the only barrier

    const f32x4 z4 = {0.f, 0.f, 0.f, 0.f};

    for (int w = 0; w < 3; ++w) {
        const ushortT* Wb2 = Wbf + ((size_t)w * NBR + n) * CHN * CHN;
        for (int ot = 0; ot < 2; ++ot) {
            f32x4 acc[4][4];
#pragma unroll
            for (int mf = 0; mf < 4; ++mf)
#pragma unroll
                for (int nf = 0; nf < 4; ++nf) acc[mf][nf] = z4;
#pragma unroll
            for (int kb = 0; kb < 4; ++kb)
                mfma_chunk_frag(sX, Wb2, ot, acc, wr, wc, lane, kb);

            const int obase = ot * 128;
            if (w < 2) {
                float* rs = (w == 0) ? qsum : ksum;
                unsigned* rm = (w == 0) ? qmax : kmax;
#pragma unroll
                for (int nf = 0; nf < 4; ++nf) {
                    float s = 0.f, m = -3.4e38f;
#pragma unroll
                    for (int mf = 0; mf < 4; ++mf)
#pragma unroll
                        for (int r = 0; r < 4; ++r) {
                            float v = acc[mf][nf][r];
                            s += v; m = fmaxf(m, v);
                        }
                    s += __shfl_xor(s, 16); s += __shfl_xor(s, 32);
                    m = fmaxf(m, __shfl_xor(m, 16)); m = fmaxf(m, __shfl_xor(m, 32));
                    if (lane < 16) {
                        int o = obase + wc * 64 + nf * 16 + lane;
                        atomicAdd(&rs[z * CHN + o], s);
                        atomicMax(&rm[z * CHN + o], encf(m));
                    }
                }
            } else {
#pragma unroll
                for (int nf = 0; nf < 4; ++nf) {
                    int o = obase + wc * 64 + nf * 16 + (lane & 15);
                    float bvv = bv[n * CHN + o];
#pragma unroll
                    for (int mf = 0; mf < 4; ++mf) {
                        int l = lbase + wr * 64 + mf * 16 + ((lane >> 4) << 2);
                        ushort4_t u;
#pragma unroll
                        for (int r = 0; r < 4; ++r) u[r] = f2bf(acc[mf][nf][r] + bvv);
                        *(ushort4_t*)(vbuf + (size_t)(z * CHN + o) * LEN + l) = u;
                    }
                }
            }
        }
    }
}

// ---------------------------------------------------------------------------
// O GEMM: agg (bf16, [z][c][l]) -> out_pre (bf16, [z][c][l]) + BN stats.
// Same structure: 1 barrier, barrier-free GEMM with fragment-order W loads.
// ---------------------------------------------------------------------------
__global__ __launch_bounds__(256, 2)
void ogemm_kernel(const ushortT* __restrict__ agg, const ushortT* __restrict__ Wbo,
                  const float* __restrict__ bo_,
                  float* __restrict__ bnsum, float* __restrict__ bnss,
                  ushortT* __restrict__ outpre)
{
    __shared__ ushortT sX[128 * 256];
    const int tid = threadIdx.x;
    const int lane = tid & 63;
    const int wv = tid >> 6;
    const int wr = wv >> 1, wc = wv & 1;
    const int lbase = blockIdx.x * 128;
    const int z = blockIdx.y;
    const int n = z >> 4;
    const ushortT* Wb2 = Wbo + (size_t)n * CHN * CHN;   // per-branch slice

    stage_x_bf16(agg, sX, z, lbase, tid);
    __syncthreads();                    // the only barrier

    const f32x4 z4 = {0.f, 0.f, 0.f, 0.f};
    for (int ot = 0; ot < 2; ++ot) {
        f32x4 acc[4][4];
#pragma unroll
        for (int mf = 0; mf < 4; ++mf)
#pragma unroll
            for (int nf = 0; nf < 4; ++nf) acc[mf][nf] = z4;
#pragma unroll
        for (int kb = 0; kb < 4; ++kb)
            mfma_chunk_frag(sX, Wb2, ot, acc, wr, wc, lane, kb);

        const int obase = ot * 128;
#pragma unroll
        for (int nf = 0; nf < 4; ++nf) {
            int o = obase + wc * 64 + nf * 16 + (lane & 15);
            float bb = bo_[n * CHN + o];
            float s = 0.f, q2 = 0.f;
#pragma unroll
            for (int mf = 0; mf < 4; ++mf) {
                int l = lbase + wr * 64 + mf * 16 + ((lane >> 4) << 2);
                ushort4_t u;
#pragma unroll
                for (int r = 0; r < 4; ++r) {
                    float v = acc[mf][nf][r] + bb;
                    u[r] = f2bf(v);
                    s += v; q2 += v * v;
                }
                *(ushort4_t*)(outpre + (size_t)(z * CHN + o) * LEN + l) = u;
            }
            s += __shfl_xor(s, 16); s += __shfl_xor(s, 32);
            q2 += __shfl_xor(q2, 16); q2 += __shfl_xor(q2, 32);
            if (lane < 16) {
                atomicAdd(&bnsum[n * CHN + o], s);
                atomicAdd(&bnss[n * CHN + o], q2);
            }
        }
    }
}

// convert all 4 weight tensors fp32 -> bf16 in MFMA-FRAGMENT order:
// Wbf[w][n][ob][cb][lane][8] with o = ob*16 + (lane&15), c = cb*32 + (lane>>4)*8 + j
__global__ void wcvt_kernel(const float* __restrict__ Wq, const float* __restrict__ Wk,
                            const float* __restrict__ Wv, const float* __restrict__ Wo,
                            ushortT* __restrict__ Wbf)
{
    int t = blockIdx.x * 256 + threadIdx.x;    // one thread per 8-elem fragment slice
    if (t < 4 * (W_EL / 8)) {
        const float* srcs[4] = {Wq, Wk, Wv, Wo};
        int w    = t >> 15;          // W_EL/8 = 32768 per tensor
        int r    = t & 32767;
        int lane = r & 63;
        int cb   = (r >> 6) & 7;
        int ob   = (r >> 9) & 15;
        int n    = r >> 13;
        const float* src = srcs[w] + (size_t)n * CHN * CHN;
        int o = ob * 16 + (lane & 15);
        int c = cb * 32 + (lane >> 4) * 8;
        float4 f0 = *(const float4*)(src + (size_t)o * CHN + c);
        float4 f1 = *(const float4*)(src + (size_t)o * CHN + c + 4);
        ushort8_t u = {f2bf(f0.x), f2bf(f0.y), f2bf(f0.z), f2bf(f0.w),
                       f2bf(f1.x), f2bf(f1.y), f2bf(f1.z), f2bf(f1.w)};
        *(ushort8_t*)(Wbf + ((size_t)w * NBR + n) * CHN * CHN
                          + (((size_t)ob * 8 + cb) * 64 + lane) * 8) = u;
    }
}

// ---------------------------------------------------------------------------
// attention coefficients: scores[i,j,b] = (sum_c sq*sk) * edge_w[i,j] / 64
// attn[i,j,b] = softmax_j(scores) * softmax(branch_imp)[j]
// sq = qsum/L + dec(qmax) + 2*bq  (mean+max, bias shifts both by bq)
// ---------------------------------------------------------------------------
__global__ void attn_kernel(const float* __restrict__ qsum, const unsigned* __restrict__ qmax,
                            const float* __restrict__ ksum, const unsigned* __restrict__ kmax,
                            const float* __restrict__ bq, const float* __restrict__ bk,
                            const float* __restrict__ edge, const float* __restrict__ bimp,
                            float* __restrict__ attn)
{
    __shared__ float sc[NBR][NBR][BSZ];
    int tid = threadIdx.x;           // 256 threads == 4*4*16
    int i = tid >> 6, j = (tid >> 4) & 3, b = tid & 15;
    float s = 0.f;
    const float invL = 1.0f / (float)LEN;
    for (int c = 0; c < CHN; ++c) {
        int qi = (i * BSZ + b) * CHN + c;
        int ki = (j * BSZ + b) * CHN + c;
        float sq = qsum[qi] * invL + decf(qmax[qi]) + 2.f * bq[i * CHN + c];
        float sk = ksum[ki] * invL + decf(kmax[ki]) + 2.f * bk[j * CHN + c];
        s += sq * sk;
    }
    sc[i][j][b] = s * edge[i * 4 + j] * (1.0f / 64.0f);
    __syncthreads();
    if (tid < 64) {
        int ii = tid >> 4, bb = tid & 15;
        float m = -3.4e38f;
        for (int jj = 0; jj < 4; ++jj) m = fmaxf(m, sc[ii][jj][bb]);
        float e[4]; float sum = 0.f;
        for (int jj = 0; jj < 4; ++jj) { e[jj] = __expf(sc[ii][jj][bb] - m); sum += e[jj]; }
        float bm = fmaxf(fmaxf(bimp[0], bimp[1]), fmaxf(bimp[2], bimp[3]));
        float be[4]; float bs = 0.f;
        for (int jj = 0; jj < 4; ++jj) { be[jj] = __expf(bimp[jj] - bm); bs += be[jj]; }
        for (int jj = 0; jj < 4; ++jj)
            attn[(ii * 4 + jj) * BSZ + bb] = (e[jj] / sum) * (be[jj] / bs);
    }
}

// agg[i,b,c,l] = sum_j attn[i,j,b] * v[j,b,c,l]   (bf16 in, bf16 out)
__global__ __launch_bounds__(256)
void agg_kernel(const ushortT* __restrict__ v, const float* __restrict__ attn,
                ushortT* __restrict__ agg)
{
    __shared__ float sa[256];
    sa[threadIdx.x] = attn[threadIdx.x];
    __syncthreads();
    const long long U = (long long)BSZ * CHN * (LEN / 8);   // 2,097,152 units of 8
    for (long long u = (long long)blockIdx.x * blockDim.x + threadIdx.x; u < U;
         u += (long long)gridDim.x * blockDim.x) {
        int l0 = (int)(u & 511) * 8;
        int c  = (int)(u >> 9) & 255;
        int b  = (int)(u >> 17);
        float vv[4][8];
#pragma unroll
        for (int j = 0; j < 4; ++j) {
            ushort8_t raw = *(const ushort8_t*)(v + (((size_t)(j * BSZ + b) * CHN + c) * LEN) + l0);
#pragma unroll
            for (int e = 0; e < 8; ++e) vv[j][e] = bf2f(raw[e]);
        }
#pragma unroll
        for (int i = 0; i < 4; ++i) {
            float a0 = sa[(i * 4 + 0) * BSZ + b];
            float a1 = sa[(i * 4 + 1) * BSZ + b];
            float a2 = sa[(i * 4 + 2) * BSZ + b];
            float a3 = sa[(i * 4 + 3) * BSZ + b];
            ushort8_t out;
#pragma unroll
            for (int e = 0; e < 8; ++e) {
                float r = a0 * vv[0][e] + a1 * vv[1][e] + a2 * vv[2][e] + a3 * vv[3][e];
                out[e] = f2bf(r);
            }
            *(ushort8_t*)(agg + (((size_t)(i * BSZ + b) * CHN + c) * LEN) + l0) = out;
        }
    }
}

// finalize BN affine: scale = gamma*rsqrt(var+eps), shift = beta - mean*scale
__global__ void bnfin_kernel(const float* __restrict__ bnsum, const float* __restrict__ bnss,
                             const float* __restrict__ gamma, const float* __restrict__ beta,
                             float* __restrict__ scl, float* __restrict__ shf)
{
    int t = blockIdx.x * blockDim.x + threadIdx.x;   // 0..1023 = n*256+c
    if (t < NBR * CHN) {
        const float inv = 1.0f / (float)BL;
        float mean = bnsum[t] * inv;
        float var = bnss[t] * inv - mean * mean;
        float rs = rsqrtf(var + BN_EPS);
        float s = gamma[t] * rs;
        scl[t] = s;
        shf[t] = beta[t] - mean * s;
    }
}

// out = relu(out_pre*scale + shift) + x
__global__ __launch_bounds__(256)
void final_kernel(const ushortT* __restrict__ outpre, const float* __restrict__ x,
                  const float* __restrict__ scl, const float* __restrict__ shf,
                  float* __restrict__ out)
{
    const long long U = (long long)NB_B * CHN * (LEN / 8);   // 8,388,608 units of 8
    for (long long u = (long long)blockIdx.x * blockDim.x + threadIdx.x; u < U;
         u += (long long)gridDim.x * blockDim.x) {
        int l0 = (int)(u & 511) * 8;
        int c  = (int)(u >> 9) & 255;
        int zz = (int)(u >> 17);          // n*16+b
        int n  = zz >> 4;
        size_t base = ((size_t)zz * CHN + c) * LEN + l0;
        ushort8_t op = *(const ushort8_t*)(outpre + base);
        float4 x0 = *(const float4*)(x + base);
        float4 x1 = *(const float4*)(x + base + 4);
        float sc = scl[n * CHN + c];
        float sh = shf[n * CHN + c];
        float xr[8] = {x0.x, x0.y, x0.z, x0.w, x1.x, x1.y, x1.z, x1.w};
        float res[8];
#pragma unroll
        for (int e = 0; e < 8; ++e) {
            float bn = bf2f(op[e]) * sc + sh;
            res[e] = fmaxf(bn, 0.f) + xr[e];
        }
        float4 o0 = {res[0], res[1], res[2], res[3]};
        float4 o1 = {res[4], res[5], res[6], res[7]};
        *(float4*)(out + base) = o0;
        *(float4*)(out + base + 4) = o1;
    }
}

extern "C" void kernel_launch(void* const* d_in, const int* in_sizes, int n_in,
                              void* d_out, int out_size, void* d_ws, size_t ws_size,
                              hipStream_t stream)
{
    const float* x     = (const float*)d_in[0];
    const float* Wq    = (const float*)d_in[1];
    const float* bq    = (const float*)d_in[2];
    const float* Wk    = (const float*)d_in[3];
    const float* bk    = (const float*)d_in[4];
    const float* Wv    = (const float*)d_in[5];
    const float* bv    = (const float*)d_in[6];
    const float* Wo    = (const float*)d_in[7];
    const float* bo    = (const float*)d_in[8];
    const float* gamma = (const float*)d_in[9];
    const float* beta  = (const float*)d_in[10];
    const float* edge  = (const float*)d_in[11];
    const float* bimp  = (const float*)d_in[12];

    char* ws = (char*)d_ws;
    const size_t V_BYTES = (size_t)NBR * BSZ * CHN * LEN * 2;   // 128 MiB (bf16)
    ushortT* vbuf = (ushortT*)ws;            // v, later reused for out_pre
    size_t off = V_BYTES;
    float*    qsum = (float*)(ws + off);    off += 65536;
    unsigned* qmax = (unsigned*)(ws + off); off += 65536;
    float*    ksum = (float*)(ws + off);    off += 65536;
    unsigned* kmax = (unsigned*)(ws + off); off += 65536;
    float*    attn = (float*)(ws + off);    off += 1024;
    float*    bnsum= (float*)(ws + off);    off += 4096;
    float*    bnss = (float*)(ws + off);    off += 4096;
    float*    scl  = (float*)(ws + off);    off += 4096;
    float*    shf  = (float*)(ws + off);    off += 4096;

    // zero the small accumulators (sum=0; max uses encoding where 0 < enc(-inf))
    hipMemsetAsync(ws + V_BYTES, 0, off - V_BYTES, stream);

    // d_out scratch usage (dead by the time final_kernel rewrites d_out):
    //   [0, 128Mi):    agg (bf16, [z][c][l]) written by agg_kernel
    //   [128Mi, +2Mi): Wbf (bf16 weights, fragment order) written by wcvt
    ushortT* aggbuf = (ushortT*)d_out;
    ushortT* Wbf = (ushortT*)((char*)d_out + ((size_t)134217728));
    float*   outf = (float*)d_out;

    wcvt_kernel<<<(4 * (W_EL / 8) + 255) / 256, 256, 0, stream>>>(Wq, Wk, Wv, Wo, Wbf);

    dim3 gq(LEN / 128, NB_B);   // (32, 64)
    qkv_kernel<<<gq, 256, 0, stream>>>(x, Wbf, bv, qsum, qmax, ksum, kmax, vbuf);
    attn_kernel<<<1, 256, 0, stream>>>(qsum, qmax, ksum, kmax, bq, bk, edge, bimp, attn);
    agg_kernel<<<2048, 256, 0, stream>>>(vbuf, attn, aggbuf);
    ogemm_kernel<<<gq, 256, 0, stream>>>(aggbuf, Wbf + (size_t)3 * W_EL, bo, bnsum, bnss, vbuf);
    bnfin_kernel<<<4, 256, 0, stream>>>(bnsum, bnss, gamma, beta, scl, shf);
    final_kernel<<<8192, 256, 0, stream>>>(vbuf, x, scl, shf, outf);
}